// Round 9
// baseline (173.212 us; speedup 1.0000x reference)
//
#include <hip/hip_runtime.h>

// Shapes: msa [1,128,256,256] f32, pair [1,256,256,128] f32, out same as pair.
// ws: leftT [256 l][4 kk][2 iLow][64 lane][8] bf16  (MFMA A-fragment-direct)
//     rightT same
//     | w3n [2 kh][32 kc][4 pg][64 lane][8 e] bf16 (32x32x16 B-fragment-direct:
//            p = pg*32 + (lane&31), k' = kh*512 + kc*16 + (lane>>5)*8 + e)
//     | wB [32 frag: nt*8+ks][64 lane][8 e] bf16 (k_lnproj B-fragment-direct)

typedef float v4f __attribute__((ext_vector_type(4)));
typedef float f32x16 __attribute__((ext_vector_type(16)));
typedef short v8s __attribute__((ext_vector_type(8)));

static __device__ inline unsigned short f2bf(float x) {
    unsigned int u = __builtin_bit_cast(unsigned int, x);
    return (unsigned short)((u + 0x7fffu + ((u >> 16) & 1u)) >> 16);
}

// global->LDS direct copy, 16 B per lane (wave-uniform LDS base + lane*16)
static __device__ inline void gl_lds16(const unsigned short* g, unsigned short* l) {
    __builtin_amdgcn_global_load_lds(
        (const __attribute__((address_space(1))) unsigned int*)g,
        (__attribute__((address_space(3))) unsigned int*)(unsigned long long)l,
        16, 0, 0);
}

// ---------------- one-time weight reformat ----------------
// blocks 0..63: w3n (32x32x16 fragment order); blocks 64..71: wB
__global__ __launch_bounds__(256) void k_prep(const float* __restrict__ w_out,
                                              const float* __restrict__ wl,
                                              const float* __restrict__ wr,
                                              unsigned short* __restrict__ w3n,
                                              unsigned short* __restrict__ wB) {
    const int b = blockIdx.x, t = threadIdx.x;
    unsigned short tmp[8];
    if (b < 64) {
        int tgt = b * 2048 + t * 8;            // linear in w3n
        int l = (tgt >> 3) & 63;
        int pg = (tgt >> 9) & 3;
        int kc = (tgt >> 11) & 31;
        int kh = (tgt >> 16) & 1;
        int p = pg * 32 + (l & 31);
        for (int e = 0; e < 8; ++e) {
            int kp = kh * 512 + kc * 16 + (l >> 5) * 8 + e;   // k' this lane-elem feeds
            int j1 = (kp >> 9) & 1, qd = (kp >> 7) & 3, lp = (kp >> 3) & 15;
            int i1 = (kp >> 2) & 1, r = kp & 3;
            int ii = i1 * 16 + qd * 4 + r, jj = j1 * 16 + lp;
            tmp[e] = f2bf(w_out[(ii * 32 + jj) * 128 + p]);
        }
        *(uint4*)&w3n[tgt] = *(const uint4*)tmp;
    } else {
        int tgt = (b - 64) * 2048 + t * 8;     // linear in wB (32 frag x 512)
        int frag = tgt >> 9, lane6 = (tgt >> 3) & 63;
        int nt = frag >> 3, ks = frag & 7;
        int quad = lane6 >> 4, l15 = lane6 & 15;
        int c = nt * 16 + l15;
        const float* src = (c < 32) ? wl : wr;
        int cc = c & 31;
        for (int e = 0; e < 8; ++e) {
            int d = ks * 32 + quad * 8 + e;
            tmp[e] = f2bf(src[d * 32 + cc]);
        }
        *(uint4*)&wB[tgt] = *(const uint4*)tmp;
    }
}

// ---------------- LayerNorm + left/right projection ----------------
// grid (256 l, 4 s-quarters), block 256. B-fragments direct from L2 (no wlds).
__global__ __launch_bounds__(256) void k_lnproj(
    const float* __restrict__ msa, const float* __restrict__ gamma, const float* __restrict__ beta,
    const unsigned short* __restrict__ wB, const float* __restrict__ bl, const float* __restrict__ br,
    unsigned short* __restrict__ leftT, unsigned short* __restrict__ rightT) {
    __shared__ unsigned short xb[32 * 264];     // [32 s][256 d + 8 pad]
    __shared__ unsigned short outT[64 * 40];    // [64 c][32 s + 8 pad]

    const int t = threadIdx.x, lane = t & 63, w = t >> 6;
    const int l = blockIdx.x, s0 = blockIdx.y * 32;
    const int quad = lane >> 4, l15 = lane & 15;

    // LayerNorm: wave does 8 rows, reduction batched for 8-way ILP
    float4 g4 = *(const float4*)&gamma[lane * 4];
    float4 be4 = *(const float4*)&beta[lane * 4];
    float4 vr[8]; float s1[8], s2[8];
    for (int r = 0; r < 8; ++r) {
        const float* row = msa + (size_t)((s0 + w * 8 + r) * 256 + l) * 256;
        vr[r] = *(const float4*)&row[lane * 4];
    }
    for (int r = 0; r < 8; ++r) {
        float4 v = vr[r];
        s1[r] = v.x + v.y + v.z + v.w;
        s2[r] = v.x * v.x + v.y * v.y + v.z * v.z + v.w * v.w;
    }
    for (int o = 32; o > 0; o >>= 1)
        for (int r = 0; r < 8; ++r) { s1[r] += __shfl_xor(s1[r], o); s2[r] += __shfl_xor(s2[r], o); }
    for (int r = 0; r < 8; ++r) {
        float mu = s1[r] * (1.f / 256);
        float rs = rsqrtf(s2[r] * (1.f / 256) - mu * mu + 1e-5f);
        float4 v = vr[r];
        ushort4 xs;
        xs.x = f2bf((v.x - mu) * rs * g4.x + be4.x);
        xs.y = f2bf((v.y - mu) * rs * g4.y + be4.y);
        xs.z = f2bf((v.z - mu) * rs * g4.z + be4.z);
        xs.w = f2bf((v.w - mu) * rs * g4.w + be4.w);
        *(ushort4*)&xb[(w * 8 + r) * 264 + lane * 4] = xs;
    }
    __syncthreads();

    // MFMA: M=32 (s), N=64 (c), K=256 — B straight from L2 (frag-direct wB)
    const int mt = w >> 1, ntb = (w & 1) * 2;
    v4f acc[2] = {};
    const int frow = (mt * 16 + l15) * 264;
    const unsigned short* wBp = wB + lane * 8;
#pragma unroll
    for (int ks = 0; ks < 8; ++ks) {
        v8s a = *(const v8s*)&xb[frow + ks * 32 + quad * 8];
        v8s b0 = *(const v8s*)&wBp[(ntb * 8 + ks) * 512];
        v8s b1 = *(const v8s*)&wBp[((ntb + 1) * 8 + ks) * 512];
        acc[0] = __builtin_amdgcn_mfma_f32_16x16x32_bf16(a, b0, acc[0], 0, 0, 0);
        acc[1] = __builtin_amdgcn_mfma_f32_16x16x32_bf16(a, b1, acc[1], 0, 0, 0);
    }

    for (int tn = 0; tn < 2; ++tn) {
        int c = (ntb + tn) * 16 + l15;
        float bias = c < 32 ? bl[c] : br[c - 32];
        float scale = c < 32 ? 1.f : (1.f / 128);
        for (int r = 0; r < 4; ++r)
            outT[c * 40 + mt * 16 + quad * 4 + r] = f2bf((acc[tn][r] + bias) * scale);
    }
    __syncthreads();

    // fragment-direct global writes
    {
        int c = t >> 2, q = t & 3;               // q = sl chunk (8 s each)
        uint4 vv = *(const uint4*)&outT[c * 40 + q * 8];
        int cc = c & 31;
        unsigned short* base = (c < 32) ? leftT : rightT;
        unsigned short* dst = base + l * 4096 + blockIdx.y * 1024
                            + (cc >> 4) * 512 + q * 128 + (cc & 15) * 8;
        *(uint4*)dst = vv;
    }
}

// ---------------- fused outer-product + w_out projection ----------------
// grid (32,64): 8x4 (l,m) = 32 px, 512 threads (8 waves). w3n read ONCE per
// block. Phase B in 32x32x16 MFMA: 1 ds_read feeds 1 big MFMA (halves LDS
// reads vs 16x16). waves: pg = w&3 (32-p slice), kh = w>>2 (512 k' half);
// kh pairs reduce through Rbuf. LDS 80 KB = Obuf 64 + Rbuf 16 (2 blocks/CU).
__global__ __launch_bounds__(512, 4) void k_outer(
    const unsigned short* __restrict__ leftT, const unsigned short* __restrict__ rightT,
    const unsigned short* __restrict__ w2g, const float* __restrict__ bout,
    const float* __restrict__ pairIn, float* __restrict__ out) {
    __shared__ alignas(16) unsigned short smem[40960];   // 80 KB
    unsigned short* Ah = smem;            // staging (one kh half): A 32 KB
    unsigned short* Bh = smem + 16384;    // B 16 KB
    unsigned short* Obuf = smem;          // [32 px][1024 k'] alias, XOR-swizzled
    float* Pbuf = (float*)smem;           // [32 px][132] f32 alias (17 KB)
    float* Rbuf = (float*)(smem + 32768); // [16 s][256] f32 (16 KB, bank-clean)

    const int t = threadIdx.x, lane = t & 63, w = t >> 6;
    const int l0 = blockIdx.x * 8, m0 = blockIdx.y * 4;
    const int wm = w & 3, wn = w >> 2;
    const int quad = lane >> 4, l15 = lane & 15;

    const unsigned short* Asrc = leftT + l0 * 4096;
    const unsigned short* Bsrc = rightT + m0 * 4096;

    // ---- phase A: staged halves (kh) via global_load_lds, fragment-direct
    v4f acc[4][4] = {};
    for (int kh = 0; kh < 2; ++kh) {
        if (kh) __syncthreads();          // kh=0 LDS reads done before overwrite
#pragma unroll
        for (int it = 0; it < 4; ++it) {  // A: 32 KB
            int x = (it * 512 + t) * 8;
            gl_lds16(&Asrc[(x >> 11) * 4096 + kh * 2048 + (x & 2047)], &Ah[x]);
        }
#pragma unroll
        for (int it = 0; it < 2; ++it) {  // B: 16 KB
            int x = (it * 512 + t) * 8;
            gl_lds16(&Bsrc[(x >> 11) * 4096 + kh * 2048 + (x & 2047)], &Bh[x]);
        }
        __syncthreads();                  // drains global_load_lds + barrier
#pragma unroll
        for (int kl = 0; kl < 2; ++kl) {
            v8s a[4], bb[4];
#pragma unroll
            for (int i = 0; i < 4; ++i)
                a[i] = *(const v8s*)&Ah[(wm * 2 + (i >> 1)) * 2048 + kl * 1024 + (i & 1) * 512 + lane * 8];
#pragma unroll
            for (int j = 0; j < 4; ++j)
                bb[j] = *(const v8s*)&Bh[(wn * 2 + (j >> 1)) * 2048 + kl * 1024 + (j & 1) * 512 + lane * 8];
#pragma unroll
            for (int i = 0; i < 4; ++i)
#pragma unroll
                for (int j = 0; j < 4; ++j)
                    acc[i][j] = __builtin_amdgcn_mfma_f32_16x16x32_bf16(a[i], bb[j], acc[i][j], 0, 0, 0);
        }
    }
    __syncthreads();   // phase-A LDS reads done before Obuf overwrite

    // ---- phase-B lane mapping + issue-early w3n frags (hide under scatter)
    const int pg = w & 3, khB = w >> 2;
    const int px = lane & 31, kB = lane >> 5;
    const int swz = (px & 7) ^ ((px & 8) << 3);
    const int gb = khB * 64 + kB;                       // granule base (kc=0)
    const unsigned short* w3p = w2g + (khB * 32 * 4 + pg) * 512 + lane * 8;
    v8s F0 = *(const v8s*)&w3p[0];                      // kc=0 (stride 2048/kc)
    v8s F1 = *(const v8s*)&w3p[2048];
    v8s F2 = *(const v8s*)&w3p[4096];
    v8s F3 = *(const v8s*)&w3p[6144];

    // ---- scatter acc -> Obuf, k' = j1*512+quad*128+l15*8+i1*4+r
    for (int a2 = 0; a2 < 2; ++a2)
        for (int b2 = 0; b2 < 2; ++b2) {
            int P = (wm * 2 + a2) * 4 + wn * 2 + b2;
            for (int j1 = 0; j1 < 2; ++j1) {
                unsigned short tmp8[8];
                for (int i1 = 0; i1 < 2; ++i1)
                    for (int r = 0; r < 4; ++r)
                        tmp8[i1 * 4 + r] = f2bf(acc[a2 * 2 + i1][b2 * 2 + j1][r]);
                int pgx = (j1 * 64 + lane) ^ (P & 7) ^ ((P & 8) << 3);
                *(uint4*)&Obuf[P * 1024 + pgx * 8] = *(const uint4*)tmp8;
            }
        }
    __syncthreads();

    // ---- phase B: 32x32x16. Wave (pg,khB): 32 kc-steps, 1 read + 1 MFMA each,
    //      4-deep rolling w3n prefetch, 2 split acc chains.
    f32x16 ac0 = {}, ac1 = {};
#pragma unroll
    for (int o = 0; o < 8; ++o) {
        {   int kc = o * 4;
            v8s a = *(const v8s*)&Obuf[px * 1024 + (((gb + kc * 2) ^ swz) << 3)];
            ac0 = __builtin_amdgcn_mfma_f32_32x32x16_bf16(a, F0, ac0, 0, 0, 0);
            if (kc + 4 < 32) F0 = *(const v8s*)&w3p[(kc + 4) * 2048];
        }
        {   int kc = o * 4 + 1;
            v8s a = *(const v8s*)&Obuf[px * 1024 + (((gb + kc * 2) ^ swz) << 3)];
            ac1 = __builtin_amdgcn_mfma_f32_32x32x16_bf16(a, F1, ac1, 0, 0, 0);
            if (kc + 4 < 32) F1 = *(const v8s*)&w3p[(kc + 4) * 2048];
        }
        {   int kc = o * 4 + 2;
            v8s a = *(const v8s*)&Obuf[px * 1024 + (((gb + kc * 2) ^ swz) << 3)];
            ac0 = __builtin_amdgcn_mfma_f32_32x32x16_bf16(a, F2, ac0, 0, 0, 0);
            if (kc + 4 < 32) F2 = *(const v8s*)&w3p[(kc + 4) * 2048];
        }
        {   int kc = o * 4 + 3;
            v8s a = *(const v8s*)&Obuf[px * 1024 + (((gb + kc * 2) ^ swz) << 3)];
            ac1 = __builtin_amdgcn_mfma_f32_32x32x16_bf16(a, F3, ac1, 0, 0, 0);
            if (kc + 4 < 32) F3 = *(const v8s*)&w3p[(kc + 4) * 2048];
        }
    }
    f32x16 accB = ac0 + ac1;

    // ---- kh=1 waves deposit partials (Rbuf disjoint from Obuf; no barrier yet)
    if (khB == 1) {
#pragma unroll
        for (int s = 0; s < 16; ++s) Rbuf[s * 256 + pg * 64 + lane] = accB[s];
    }

    // ---- issue pairIn loads (wave's 4 full rows; overlap reduction+transpose)
    const float* psrc = pairIn + (size_t)((l0 + w) * 256 + m0) * 128 + lane * 2;
    float2 pp[4];
#pragma unroll
    for (int sub = 0; sub < 4; ++sub) pp[sub] = *(const float2*)&psrc[sub * 128];

    __syncthreads();   // Rbuf ready; all Obuf reads done before Pbuf overwrite

    // ---- kh=0 waves: reduce + bias + transpose into Pbuf[px][p]
    if (khB == 0) {
        float bo = bout[pg * 32 + px];
#pragma unroll
        for (int s = 0; s < 16; ++s) {
            float v = accB[s] + Rbuf[s * 256 + pg * 64 + lane] + bo;
            int pxr = (s & 3) + 8 * (s >> 2) + 4 * kB;
            Pbuf[pxr * 132 + pg * 32 + px] = v;
        }
    }
    __syncthreads();

    // ---- epilogue: wave writes its 4 FULL 512B rows (line-merged traffic)
    float* odst = out + (size_t)((l0 + w) * 256 + m0) * 128 + lane * 2;
#pragma unroll
    for (int sub = 0; sub < 4; ++sub) {
        int P = w * 4 + sub;
        float2 pv = *(const float2*)&Pbuf[P * 132 + lane * 2];
        float2 ov;
        ov.x = pp[sub].x + pv.x;
        ov.y = pp[sub].y + pv.y;
        *(float2*)&odst[sub * 128] = ov;
    }
}

extern "C" void kernel_launch(void* const* d_in, const int* in_sizes, int n_in,
                              void* d_out, int out_size, void* d_ws, size_t ws_size,
                              hipStream_t stream) {
    const float* msa   = (const float*)d_in[0];
    const float* pairI = (const float*)d_in[1];
    const float* gamma = (const float*)d_in[4];
    const float* beta  = (const float*)d_in[5];
    const float* wl    = (const float*)d_in[6];
    const float* bl    = (const float*)d_in[7];
    const float* wr    = (const float*)d_in[8];
    const float* br    = (const float*)d_in[9];
    const float* wout  = (const float*)d_in[10];
    const float* bout  = (const float*)d_in[11];
    float* out = (float*)d_out;

    unsigned short* leftT  = (unsigned short*)d_ws;
    unsigned short* rightT = leftT + 256 * 32 * 128;
    unsigned short* w3n    = rightT + 256 * 32 * 128;
    unsigned short* wB     = w3n + 131072;

    k_prep<<<dim3(72), 256, 0, stream>>>(wout, wl, wr, w3n, wB);
    k_lnproj<<<dim3(256, 4), 256, 0, stream>>>(msa, gamma, beta, wB, bl, br, leftT, rightT);
    k_outer<<<dim3(32, 64), 512, 0, stream>>>(leftT, rightT, w3n, bout, pairI, out);
}

// Round 10
// 162.266 us; speedup vs baseline: 1.0675x; 1.0675x over previous
//
#include <hip/hip_runtime.h>

// Shapes: msa [1,128,256,256] f32, pair [1,256,256,128] f32, out same as pair.
// ws: leftT [256 l][4 kk][2 iLow][64 lane][8] bf16  (MFMA A-fragment-direct)
//     rightT same
//     | w3 [2 khB][16 ksl][4 pg][2 tt][64 lane][8 e] bf16 (B-fragment-direct:
//          p = pg*32 + tt*16 + (lane&15), k' = (khB*16+ksl)*32 + (lane>>4)*8 + e)
//     | wB [32 frag: nt*8+ks][64 lane][8 e] bf16 (k_lnproj B-fragment-direct)

typedef float v4f __attribute__((ext_vector_type(4)));
typedef short v8s __attribute__((ext_vector_type(8)));

static __device__ inline unsigned short f2bf(float x) {
    unsigned int u = __builtin_bit_cast(unsigned int, x);
    return (unsigned short)((u + 0x7fffu + ((u >> 16) & 1u)) >> 16);
}

// global->LDS direct copy, 16 B per lane (wave-uniform LDS base + lane*16)
static __device__ inline void gl_lds16(const unsigned short* g, unsigned short* l) {
    __builtin_amdgcn_global_load_lds(
        (const __attribute__((address_space(1))) unsigned int*)g,
        (__attribute__((address_space(3))) unsigned int*)(unsigned long long)l,
        16, 0, 0);
}

// ---------------- one-time weight reformat ----------------
// blocks 0..63: w3 (kh-split fragment order); blocks 64..71: wB
__global__ __launch_bounds__(256) void k_prep(const float* __restrict__ w_out,
                                              const float* __restrict__ wl,
                                              const float* __restrict__ wr,
                                              unsigned short* __restrict__ w3,
                                              unsigned short* __restrict__ wB) {
    const int b = blockIdx.x, t = threadIdx.x;
    unsigned short tmp[8];
    if (b < 64) {
        int tgt = b * 2048 + t * 8;            // linear in w3
        int lane6 = (tgt >> 3) & 63;
        int tt = (tgt >> 9) & 1;
        int pg = (tgt >> 10) & 3;
        int ksl = (tgt >> 12) & 15;
        int khB = (tgt >> 16) & 1;
        int p = pg * 32 + tt * 16 + (lane6 & 15);
        int kbase = (khB * 16 + ksl) * 32 + (lane6 >> 4) * 8;
        for (int e = 0; e < 8; ++e) {
            int kp = kbase + e;                // k' this lane-element feeds
            int j1 = (kp >> 9) & 1, qd = (kp >> 7) & 3, lp = (kp >> 3) & 15;
            int i1 = (kp >> 2) & 1, r = kp & 3;
            int ii = i1 * 16 + qd * 4 + r, jj = j1 * 16 + lp;
            tmp[e] = f2bf(w_out[(ii * 32 + jj) * 128 + p]);
        }
        *(uint4*)&w3[tgt] = *(const uint4*)tmp;
    } else {
        int tgt = (b - 64) * 2048 + t * 8;     // linear in wB (32 frag x 512)
        int frag = tgt >> 9, lane6 = (tgt >> 3) & 63;
        int nt = frag >> 3, ks = frag & 7;
        int quad = lane6 >> 4, l15 = lane6 & 15;
        int c = nt * 16 + l15;
        const float* src = (c < 32) ? wl : wr;
        int cc = c & 31;
        for (int e = 0; e < 8; ++e) {
            int d = ks * 32 + quad * 8 + e;
            tmp[e] = f2bf(src[d * 32 + cc]);
        }
        *(uint4*)&wB[tgt] = *(const uint4*)tmp;
    }
}

// ---------------- LayerNorm + left/right projection ----------------
// grid (256 l, 4 s-quarters), block 256. B-fragments direct from L2 (no wlds).
__global__ __launch_bounds__(256) void k_lnproj(
    const float* __restrict__ msa, const float* __restrict__ gamma, const float* __restrict__ beta,
    const unsigned short* __restrict__ wB, const float* __restrict__ bl, const float* __restrict__ br,
    unsigned short* __restrict__ leftT, unsigned short* __restrict__ rightT) {
    __shared__ unsigned short xb[32 * 264];     // [32 s][256 d + 8 pad]
    __shared__ unsigned short outT[64 * 40];    // [64 c][32 s + 8 pad]

    const int t = threadIdx.x, lane = t & 63, w = t >> 6;
    const int l = blockIdx.x, s0 = blockIdx.y * 32;
    const int quad = lane >> 4, l15 = lane & 15;

    // LayerNorm: wave does 8 rows, reduction batched for 8-way ILP
    float4 g4 = *(const float4*)&gamma[lane * 4];
    float4 be4 = *(const float4*)&beta[lane * 4];
    float4 vr[8]; float s1[8], s2[8];
    for (int r = 0; r < 8; ++r) {
        const float* row = msa + (size_t)((s0 + w * 8 + r) * 256 + l) * 256;
        vr[r] = *(const float4*)&row[lane * 4];
    }
    for (int r = 0; r < 8; ++r) {
        float4 v = vr[r];
        s1[r] = v.x + v.y + v.z + v.w;
        s2[r] = v.x * v.x + v.y * v.y + v.z * v.z + v.w * v.w;
    }
    for (int o = 32; o > 0; o >>= 1)
        for (int r = 0; r < 8; ++r) { s1[r] += __shfl_xor(s1[r], o); s2[r] += __shfl_xor(s2[r], o); }
    for (int r = 0; r < 8; ++r) {
        float mu = s1[r] * (1.f / 256);
        float rs = rsqrtf(s2[r] * (1.f / 256) - mu * mu + 1e-5f);
        float4 v = vr[r];
        ushort4 xs;
        xs.x = f2bf((v.x - mu) * rs * g4.x + be4.x);
        xs.y = f2bf((v.y - mu) * rs * g4.y + be4.y);
        xs.z = f2bf((v.z - mu) * rs * g4.z + be4.z);
        xs.w = f2bf((v.w - mu) * rs * g4.w + be4.w);
        *(ushort4*)&xb[(w * 8 + r) * 264 + lane * 4] = xs;
    }
    __syncthreads();

    // MFMA: M=32 (s), N=64 (c), K=256 — B straight from L2 (frag-direct wB)
    const int mt = w >> 1, ntb = (w & 1) * 2;
    v4f acc[2] = {};
    const int frow = (mt * 16 + l15) * 264;
    const unsigned short* wBp = wB + lane * 8;
#pragma unroll
    for (int ks = 0; ks < 8; ++ks) {
        v8s a = *(const v8s*)&xb[frow + ks * 32 + quad * 8];
        v8s b0 = *(const v8s*)&wBp[(ntb * 8 + ks) * 512];
        v8s b1 = *(const v8s*)&wBp[((ntb + 1) * 8 + ks) * 512];
        acc[0] = __builtin_amdgcn_mfma_f32_16x16x32_bf16(a, b0, acc[0], 0, 0, 0);
        acc[1] = __builtin_amdgcn_mfma_f32_16x16x32_bf16(a, b1, acc[1], 0, 0, 0);
    }

    for (int tn = 0; tn < 2; ++tn) {
        int c = (ntb + tn) * 16 + l15;
        float bias = c < 32 ? bl[c] : br[c - 32];
        float scale = c < 32 ? 1.f : (1.f / 128);
        for (int r = 0; r < 4; ++r)
            outT[c * 40 + mt * 16 + quad * 4 + r] = f2bf((acc[tn][r] + bias) * scale);
    }
    __syncthreads();

    // fragment-direct global writes
    {
        int c = t >> 2, q = t & 3;               // q = sl chunk (8 s each)
        uint4 vv = *(const uint4*)&outT[c * 40 + q * 8];
        int cc = c & 31;
        unsigned short* base = (c < 32) ? leftT : rightT;
        unsigned short* dst = base + l * 4096 + blockIdx.y * 1024
                            + (cc >> 4) * 512 + q * 128 + (cc & 15) * 8;
        *(uint4*)dst = vv;
    }
}

// ---------------- fused outer-product + w_out projection ----------------
// grid (32,64): 8x4 (l,m) = 32 px, 512 threads (8 waves). w3 read ONCE per
// block. Phase B kh-split: wave = (pg 32-p slice, khB 512-k' half); each
// a-read feeds 2 MFMAs (tt0/tt1) -> block a-reads halved (512->256) at R8's
// register profile (16-f32 acc). kh partials reduced through Rbuf.
// LDS 80 KB = Obuf 64 + Rbuf 16 (2 blocks/CU). Pbuf full-line epilogue (R8).
__global__ __launch_bounds__(512, 4) void k_outer(
    const unsigned short* __restrict__ leftT, const unsigned short* __restrict__ rightT,
    const unsigned short* __restrict__ w2g, const float* __restrict__ bout,
    const float* __restrict__ pairIn, float* __restrict__ out) {
    __shared__ alignas(16) unsigned short smem[40960];   // 80 KB
    unsigned short* Ah = smem;            // staging (one kh half): A 32 KB
    unsigned short* Bh = smem + 16384;    // B 16 KB
    unsigned short* Obuf = smem;          // [32 px][1024 k'] alias, XOR-swizzled
    float* Pbuf = (float*)smem;           // [32 px][132] f32 alias (17 KB)
    float* Rbuf = (float*)(smem + 32768); // [16 sid][256 (pg,lane)] f32 (16 KB)

    const int t = threadIdx.x, lane = t & 63, w = t >> 6;
    const int l0 = blockIdx.x * 8, m0 = blockIdx.y * 4;
    const int wm = w & 3, wn = w >> 2;
    const int quad = lane >> 4, l15 = lane & 15;

    const unsigned short* Asrc = leftT + l0 * 4096;
    const unsigned short* Bsrc = rightT + m0 * 4096;

    // ---- phase A: staged halves (kh) via global_load_lds, fragment-direct
    v4f acc[4][4] = {};
    for (int kh = 0; kh < 2; ++kh) {
        if (kh) __syncthreads();          // kh=0 LDS reads done before overwrite
#pragma unroll
        for (int it = 0; it < 4; ++it) {  // A: 32 KB
            int x = (it * 512 + t) * 8;
            gl_lds16(&Asrc[(x >> 11) * 4096 + kh * 2048 + (x & 2047)], &Ah[x]);
        }
#pragma unroll
        for (int it = 0; it < 2; ++it) {  // B: 16 KB
            int x = (it * 512 + t) * 8;
            gl_lds16(&Bsrc[(x >> 11) * 4096 + kh * 2048 + (x & 2047)], &Bh[x]);
        }
        __syncthreads();                  // drains global_load_lds + barrier
#pragma unroll
        for (int kl = 0; kl < 2; ++kl) {
            v8s a[4], bb[4];
#pragma unroll
            for (int i = 0; i < 4; ++i)
                a[i] = *(const v8s*)&Ah[(wm * 2 + (i >> 1)) * 2048 + kl * 1024 + (i & 1) * 512 + lane * 8];
#pragma unroll
            for (int j = 0; j < 4; ++j)
                bb[j] = *(const v8s*)&Bh[(wn * 2 + (j >> 1)) * 2048 + kl * 1024 + (j & 1) * 512 + lane * 8];
#pragma unroll
            for (int i = 0; i < 4; ++i)
#pragma unroll
                for (int j = 0; j < 4; ++j)
                    acc[i][j] = __builtin_amdgcn_mfma_f32_16x16x32_bf16(a[i], bb[j], acc[i][j], 0, 0, 0);
        }
    }
    __syncthreads();   // phase-A LDS reads done before Obuf overwrite

    // ---- phase-B mapping + issue-early: ksl=0/1 w3 frags + biases
    const int pg = w & 3, khB = w >> 2;
    const int swzB = (l15 & 7) ^ ((l15 & 8) << 3);   // same for px and px+16
    const unsigned short* w3p = w2g + (khB * 128 + pg * 2) * 512 + lane * 8;
    v8s F0 = *(const v8s*)&w3p[0];          // (ksl=0, tt0)
    v8s F1 = *(const v8s*)&w3p[512];        // (ksl=0, tt1)
    v8s G0 = *(const v8s*)&w3p[4096];       // (ksl=1, tt0)
    v8s G1 = *(const v8s*)&w3p[4096 + 512]; // (ksl=1, tt1)
    float bo0 = bout[pg * 32 + l15];
    float bo1 = bout[pg * 32 + 16 + l15];

    // ---- scatter acc -> Obuf, k' = j1*512+quad*128+l15*8+i1*4+r
    for (int a2 = 0; a2 < 2; ++a2)
        for (int b2 = 0; b2 < 2; ++b2) {
            int P = (wm * 2 + a2) * 4 + wn * 2 + b2;
            for (int j1 = 0; j1 < 2; ++j1) {
                unsigned short tmp8[8];
                for (int i1 = 0; i1 < 2; ++i1)
                    for (int r = 0; r < 4; ++r)
                        tmp8[i1 * 4 + r] = f2bf(acc[a2 * 2 + i1][b2 * 2 + j1][r]);
                int pgx = (j1 * 64 + lane) ^ (P & 7) ^ ((P & 8) << 3);
                *(uint4*)&Obuf[P * 1024 + pgx * 8] = *(const uint4*)tmp8;
            }
        }
    __syncthreads();

    // ---- phase B: wave (pg,khB) computes P[32 px][32 p] partial over 512 k'.
    //      Per k-step: 2 a-reads feed 4 MFMAs. 2-deep rolling w3 prefetch.
    v4f a00 = {}, a01 = {}, a10 = {}, a11 = {};   // [pxt][tt]
#pragma unroll
    for (int kk2 = 0; kk2 < 8; ++kk2) {
        {   // even ksl = kk2*2 : F-set
            int g = (khB * 16 + kk2 * 2) * 4 + quad;
            int off = (g ^ swzB) << 3;
            v8s a0 = *(const v8s*)&Obuf[l15 * 1024 + off];
            v8s a1 = *(const v8s*)&Obuf[(16 + l15) * 1024 + off];
            a00 = __builtin_amdgcn_mfma_f32_16x16x32_bf16(a0, F0, a00, 0, 0, 0);
            a10 = __builtin_amdgcn_mfma_f32_16x16x32_bf16(a1, F0, a10, 0, 0, 0);
            a01 = __builtin_amdgcn_mfma_f32_16x16x32_bf16(a0, F1, a01, 0, 0, 0);
            a11 = __builtin_amdgcn_mfma_f32_16x16x32_bf16(a1, F1, a11, 0, 0, 0);
            if (kk2 < 7) {
                const unsigned short* nx = w3p + (kk2 * 2 + 2) * 4096;
                F0 = *(const v8s*)&nx[0];
                F1 = *(const v8s*)&nx[512];
            }
        }
        {   // odd ksl = kk2*2+1 : G-set
            int g = (khB * 16 + kk2 * 2 + 1) * 4 + quad;
            int off = (g ^ swzB) << 3;
            v8s a0 = *(const v8s*)&Obuf[l15 * 1024 + off];
            v8s a1 = *(const v8s*)&Obuf[(16 + l15) * 1024 + off];
            a00 = __builtin_amdgcn_mfma_f32_16x16x32_bf16(a0, G0, a00, 0, 0, 0);
            a10 = __builtin_amdgcn_mfma_f32_16x16x32_bf16(a1, G0, a10, 0, 0, 0);
            a01 = __builtin_amdgcn_mfma_f32_16x16x32_bf16(a0, G1, a01, 0, 0, 0);
            a11 = __builtin_amdgcn_mfma_f32_16x16x32_bf16(a1, G1, a11, 0, 0, 0);
            if (kk2 < 7) {
                const unsigned short* nx = w3p + (kk2 * 2 + 3) * 4096;
                G0 = *(const v8s*)&nx[0];
                G1 = *(const v8s*)&nx[512];
            }
        }
    }

    // ---- kh=1 waves deposit partials into Rbuf (disjoint from Obuf; no barrier yet)
    if (khB == 1) {
#pragma unroll
        for (int r = 0; r < 4; ++r) {
            Rbuf[(r) * 256 + pg * 64 + lane]      = a00[r];
            Rbuf[(4 + r) * 256 + pg * 64 + lane]  = a01[r];
            Rbuf[(8 + r) * 256 + pg * 64 + lane]  = a10[r];
            Rbuf[(12 + r) * 256 + pg * 64 + lane] = a11[r];
        }
    }

    // ---- issue pairIn loads (wave's 4 full rows; overlap reduction+transpose)
    const float* psrc = pairIn + (size_t)((l0 + w) * 256 + m0) * 128 + lane * 2;
    float2 pp[4];
#pragma unroll
    for (int sub = 0; sub < 4; ++sub) pp[sub] = *(const float2*)&psrc[sub * 128];

    __syncthreads();   // Rbuf ready; all Obuf reads done before Pbuf overwrite

    // ---- kh=0 waves: add partials + bias, transpose into Pbuf[px][p]
    if (khB == 0) {
#pragma unroll
        for (int r = 0; r < 4; ++r) {
            int px0r = quad * 4 + r, px1r = 16 + quad * 4 + r;
            Pbuf[px0r * 132 + pg * 32 + l15]      = a00[r] + Rbuf[(r) * 256 + pg * 64 + lane] + bo0;
            Pbuf[px0r * 132 + pg * 32 + 16 + l15] = a01[r] + Rbuf[(4 + r) * 256 + pg * 64 + lane] + bo1;
            Pbuf[px1r * 132 + pg * 32 + l15]      = a10[r] + Rbuf[(8 + r) * 256 + pg * 64 + lane] + bo0;
            Pbuf[px1r * 132 + pg * 32 + 16 + l15] = a11[r] + Rbuf[(12 + r) * 256 + pg * 64 + lane] + bo1;
        }
    }
    __syncthreads();

    // ---- epilogue: wave writes its 4 FULL 512B rows (line-merged traffic)
    float* odst = out + (size_t)((l0 + w) * 256 + m0) * 128 + lane * 2;
#pragma unroll
    for (int sub = 0; sub < 4; ++sub) {
        int P = w * 4 + sub;
        float2 pv = *(const float2*)&Pbuf[P * 132 + lane * 2];
        float2 ov;
        ov.x = pp[sub].x + pv.x;
        ov.y = pp[sub].y + pv.y;
        *(float2*)&odst[sub * 128] = ov;
    }
}

extern "C" void kernel_launch(void* const* d_in, const int* in_sizes, int n_in,
                              void* d_out, int out_size, void* d_ws, size_t ws_size,
                              hipStream_t stream) {
    const float* msa   = (const float*)d_in[0];
    const float* pairI = (const float*)d_in[1];
    const float* gamma = (const float*)d_in[4];
    const float* beta  = (const float*)d_in[5];
    const float* wl    = (const float*)d_in[6];
    const float* bl    = (const float*)d_in[7];
    const float* wr    = (const float*)d_in[8];
    const float* br    = (const float*)d_in[9];
    const float* wout  = (const float*)d_in[10];
    const float* bout  = (const float*)d_in[11];
    float* out = (float*)d_out;

    unsigned short* leftT  = (unsigned short*)d_ws;
    unsigned short* rightT = leftT + 256 * 32 * 128;
    unsigned short* w3     = rightT + 256 * 32 * 128;
    unsigned short* wB     = w3 + 131072;

    k_prep<<<dim3(72), 256, 0, stream>>>(wout, wl, wr, w3, wB);
    k_lnproj<<<dim3(256, 4), 256, 0, stream>>>(msa, gamma, beta, wB, bl, br, leftT, rightT);
    k_outer<<<dim3(32, 64), 512, 0, stream>>>(leftT, rightT, w3, bout, pairI, out);
}